// Round 4
// baseline (467.527 us; speedup 1.0000x reference)
//
#include <hip/hip_runtime.h>

// HingeRankLoss on MI355X — round 4 (same design as rounds 1-3; all prior
// submissions died to container-acquisition/infra failures before producing a
// kernel verdict — audit found no hang/OOB/capture hazard, so resubmitting).
// B=32768 rows, L=2048 cols. scores fp32, candidate_lengths int32, labels int32.
//
// Design: ONE WAVE (64 lanes) per row, 32 elements/lane, grid-stride persistent
// blocks (2048 blocks x 4 waves = 8192 waves, ~4 rows/wave).
//  - no __syncthreads, no LDS in the hot kernel: all reductions are 64-lane
//    shfl_xor butterflies
//  - loads are unconditional with clamped chunk index (row storage is full
//    L=2048, so reading past len within the row is safe; clamped lanes all hit
//    the same 16B line -> broadcast transaction)
//  - wave-uniform skip of fully-invalid 256-element chunks (len is uniform
//    across the wave since the wave owns the row)
//  - neg_cnt derived as len - npos (valid count == len), no extra reduction
//  - one atomic pair per WAVE (accumulated over its rows), spread over buckets

constexpr int L_DIM = 2048;
constexpr float MARGIN = 0.1f;
constexpr int NBUCKET = 1024;
constexpr int ROWS_PER_BLOCK = 4;   // 4 waves/block, 1 wave per row
constexpr int MAX_BLOCKS = 2048;    // memory-bound: cap grid, stride the rest

typedef float f4 __attribute__((ext_vector_type(4)));
typedef int   i4 __attribute__((ext_vector_type(4)));

__global__ __launch_bounds__(256) void hinge_row_kernel(
    const float* __restrict__ scores,
    const int*   __restrict__ lens,
    const int*   __restrict__ labels,
    float* __restrict__ acc_sum,   // [NBUCKET]
    float* __restrict__ acc_cnt,   // [NBUCKET]
    int B)
{
    const int t    = threadIdx.x;
    const int wave = t >> 6;
    const int lane = t & 63;
    const int wid     = blockIdx.x * ROWS_PER_BLOCK + wave;
    const int wstride = gridDim.x * ROWS_PER_BLOCK;

    float wsum = 0.f;   // sum of per_sample over this wave's rows
    float wcnt = 0.f;   // number of valid observations

    for (int row = wid; row < B; row += wstride) {
        int len = lens[row];                  // wave-uniform (one row per wave)
        if (len <= 0) continue;               // no barriers -> safe to diverge
        if (len > L_DIM) len = L_DIM;

        const size_t base = (size_t)row * L_DIM;
        const f4* s4 = reinterpret_cast<const f4*>(scores + base);
        const i4* l4 = reinterpret_cast<const i4*>(labels + base);
        const int vmax = (len - 1) >> 2;      // last valid float4 chunk

        float sc[32];                         // neg scores; sentinel if inactive
        float pos_local  = 0.f;
        float npos_local = 0.f;

        #pragma unroll
        for (int k = 0; k < 8; ++k) {
            #pragma unroll
            for (int e = 0; e < 4; ++e) sc[4 * k + e] = -1e30f;
            // chunk k covers columns [k*256, k*256+255]; skip if wholly invalid
            if ((k << 8) < len) {             // wave-uniform branch
                const int v  = lane + (k << 6);
                const int vc = (v < vmax) ? v : vmax;   // clamp: safe over-read
                const f4 sv = s4[vc];
                const i4 lv = l4[vc];
                #pragma unroll
                for (int e = 0; e < 4; ++e) {
                    const int  jj    = (v << 2) + e;    // true column index
                    const bool valid = jj < len;
                    const bool isp   = valid && (lv[e] == 1);
                    if (isp) { pos_local += sv[e]; npos_local += 1.f; }
                    if (valid && !isp) sc[4 * k + e] = sv[e];
                }
            }
        }

        // wave butterfly: pos score + positive count (all lanes get result)
        float p = pos_local, np = npos_local;
        #pragma unroll
        for (int off = 1; off < 64; off <<= 1) {
            p  += __shfl_xor(p,  off, 64);
            np += __shfl_xor(np, off, 64);
        }
        const float chosen = (np > 0.f) ? p : -MARGIN;

        // hinge over negatives; sentinel slots contribute exactly 0
        float h = 0.f;
        #pragma unroll
        for (int i = 0; i < 32; ++i)
            h += fmaxf(MARGIN + sc[i] - chosen, 0.f);
        #pragma unroll
        for (int off = 1; off < 64; off <<= 1)
            h += __shfl_xor(h, off, 64);

        const float negc = (float)len - np;   // valid count == len
        if (negc > 0.f) {                     // valid_obs: len>0 && has_neg
            wsum += h / negc;
            wcnt += 1.f;
        }
    }

    if (lane == 0 && wcnt > 0.f) {
        atomicAdd(&acc_sum[wid & (NBUCKET - 1)], wsum);
        atomicAdd(&acc_cnt[wid & (NBUCKET - 1)], wcnt);
    }
}

__global__ __launch_bounds__(1024) void finalize_kernel(
    const float* __restrict__ acc_sum,
    const float* __restrict__ acc_cnt,
    float* __restrict__ out)
{
    const int t = threadIdx.x;
    float s = acc_sum[t];
    float c = acc_cnt[t];
    #pragma unroll
    for (int off = 32; off > 0; off >>= 1) {
        s += __shfl_down(s, off, 64);
        c += __shfl_down(c, off, 64);
    }
    __shared__ float sh_s[16], sh_c[16];
    const int wave = t >> 6, lane = t & 63;
    if (lane == 0) { sh_s[wave] = s; sh_c[wave] = c; }
    __syncthreads();
    if (t == 0) {
        float S = 0.f, C = 0.f;
        #pragma unroll
        for (int i = 0; i < 16; ++i) { S += sh_s[i]; C += sh_c[i]; }
        out[0] = (C > 0.f) ? (S / C) : 0.f;
    }
}

extern "C" void kernel_launch(void* const* d_in, const int* in_sizes, int n_in,
                              void* d_out, int out_size, void* d_ws, size_t ws_size,
                              hipStream_t stream) {
    const float* scores = (const float*)d_in[0];
    const int*   lens   = (const int*)d_in[1];
    const int*   labels = (const int*)d_in[2];
    const int B = in_sizes[1];                 // candidate_lengths element count

    float* acc_sum = (float*)d_ws;
    float* acc_cnt = acc_sum + NBUCKET;

    // d_ws is re-poisoned 0xAA before every timed launch: zero our buckets.
    hipMemsetAsync(d_ws, 0, 2 * NBUCKET * sizeof(float), stream);

    int nblocks = (B + ROWS_PER_BLOCK - 1) / ROWS_PER_BLOCK;
    if (nblocks > MAX_BLOCKS) nblocks = MAX_BLOCKS;
    hinge_row_kernel<<<nblocks, 256, 0, stream>>>(scores, lens, labels,
                                                  acc_sum, acc_cnt, B);
    finalize_kernel<<<1, NBUCKET, 0, stream>>>(acc_sum, acc_cnt, (float*)d_out);
}